// Round 2
// baseline (8057.863 us; speedup 1.0000x reference)
//
#include <hip/hip_runtime.h>
#include <math.h>

#define D 32
#define CD 16
#define HID 64
#define DIN 48
#define TPAD 36            // padded row stride: 144B, 16B-aligned
#define IPB 8              // items per 256-thread block (1 item per 32 lanes)

// Compiler-only memory fence: DS ops from one wave are processed in order by
// the LDS pipe; all LDS traffic here is within one 32-lane half of a wave64,
// so a compiler reorder barrier is sufficient (no s_barrier needed).
#define MEMFENCE() __asm__ volatile("" ::: "memory")

static __device__ __forceinline__ float fast_rcp(float x) {
#if __has_builtin(__builtin_amdgcn_rcpf)
    return __builtin_amdgcn_rcpf(x);
#else
    return 1.0f / x;
#endif
}

// tanh(x) = 1 - 2/(exp(2x)+1); exact at +-inf, ~1e-6 abs error.
static __device__ __forceinline__ float fast_tanh(float x) {
    float e = __expf(2.0f * x);
    return 1.0f - 2.0f * fast_rcp(e + 1.0f);
}

// ---- Gauss-Jordan, column-oriented, pivot-free (S is SPD) ----------------
// Lane c holds column c of S (s[i]) and of the RHS (wc[i], init = HP[:,c]).
// Step K: lane K publishes u[i] = S[i][K]/S[K][K] (u[K] slot carries 1/pk);
// every lane: s[i] -= u[i]*s[K], wc[i] -= u[i]*wc[K] (i != K), then
// normalizes its row-K element. After 32 steps S -> I, wc = (S^-1 HP)[:,c].
// Template recursion guarantees K is a compile-time constant: every register
// array index is static, so s/wc cannot be demoted to scratch.
template <int K>
static __device__ __forceinline__ void gj_step(float (&s)[D], float (&wc)[D],
                                               float* __restrict__ Ub, int c) {
    if (c == K) {
        float pinv = fast_rcp(s[K]);
        #pragma unroll
        for (int i4 = 0; i4 < D / 4; ++i4) {
            float4 u;
            u.x = (4 * i4 + 0 == K) ? pinv : s[4 * i4 + 0] * pinv;
            u.y = (4 * i4 + 1 == K) ? pinv : s[4 * i4 + 1] * pinv;
            u.z = (4 * i4 + 2 == K) ? pinv : s[4 * i4 + 2] * pinv;
            u.w = (4 * i4 + 3 == K) ? pinv : s[4 * i4 + 3] * pinv;
            ((float4*)Ub)[i4] = u;
        }
    }
    MEMFENCE();
    float sk = s[K], wk = wc[K];
    float pinv = Ub[K];
    #pragma unroll
    for (int i4 = 0; i4 < D / 4; ++i4) {
        float4 u = ((const float4*)Ub)[i4];
        const int i0 = 4 * i4;
        if (i0 + 0 != K) { s[i0 + 0] = fmaf(-u.x, sk, s[i0 + 0]); wc[i0 + 0] = fmaf(-u.x, wk, wc[i0 + 0]); }
        if (i0 + 1 != K) { s[i0 + 1] = fmaf(-u.y, sk, s[i0 + 1]); wc[i0 + 1] = fmaf(-u.y, wk, wc[i0 + 1]); }
        if (i0 + 2 != K) { s[i0 + 2] = fmaf(-u.z, sk, s[i0 + 2]); wc[i0 + 2] = fmaf(-u.z, wk, wc[i0 + 2]); }
        if (i0 + 3 != K) { s[i0 + 3] = fmaf(-u.w, sk, s[i0 + 3]); wc[i0 + 3] = fmaf(-u.w, wk, wc[i0 + 3]); }
    }
    s[K]  = sk * pinv;
    wc[K] = wk * pinv;
    MEMFENCE();
}

template <int K>
static __device__ __forceinline__ void gj_all(float (&s)[D], float (&wc)[D],
                                              float* __restrict__ Ub, int c) {
    if constexpr (K < D) {
        gj_step<K>(s, wc, Ub, c);
        gj_all<K + 1>(s, wc, Ub, c);
    }
}

// LDS/block = 8*(32*36 + 112)*4 = 40448 B -> 4 blocks/CU.
// Peak register live set by construction:
//   S-build: mr[32]+s[32]=64 | GJ: s[32]+wc[32]=64 | epilogue: wc[32]+acc[32]=64
// (+ ~12 temps) -> fits the 128-VGPR cap of __launch_bounds__(256,4), no spill.
__global__ __launch_bounds__(256, 4) void kalman_step_kernel(
    const float* __restrict__ x_post,
    const float* __restrict__ P_post,
    const float* __restrict__ ctx,
    const float* __restrict__ meas,
    const float* __restrict__ W1,
    const float* __restrict__ b1,
    const float* __restrict__ W2,
    const float* __restrict__ b2,
    const float* __restrict__ Hm,
    const float* __restrict__ logQ,
    const float* __restrict__ logR,
    float* __restrict__ out,
    int B)
{
    __shared__ float Tbuf[IPB][D * TPAD];      // HP rows (persist to epilogue)
    __shared__ float Sbuf[IPB][DIN + HID];     // phase-multiplexed scratch

    const int t = threadIdx.x;
    const int slot = t >> 5;     // item slot within block
    const int c = t & 31;        // lane-within-item: column index
    const int item = blockIdx.x * IPB + slot;
    if (item >= B) return;

    float* Ts = Tbuf[slot];
    float* Sb = Sbuf[slot];
    // Sb timeline: [0..47] xc -> [0..31] x_pred ; [32..63] y ; [64..95] GJ u.
    float* Yb = Sb + D;
    float* Ub = Sb + 2 * D;
    float* Hb = Sb + DIN;        // h at [48..111] (dead before y/u clobber it)

    // ---------------- MLP predict: h = tanh(W1 [x;ctx] + b1); x_pred = W2 h + b2
    Sb[c] = x_post[(size_t)item * D + c];
    if (c < CD) Sb[D + c] = ctx[(size_t)item * CD + c];
    MEMFENCE();

    float a0 = b1[c], a1 = b1[c + 32];
    {
        const float4* Xq  = (const float4*)Sb;
        const float4* W1a = (const float4*)(W1 + c * DIN);
        const float4* W1b = (const float4*)(W1 + (c + 32) * DIN);
        #pragma unroll
        for (int j4 = 0; j4 < DIN / 4; ++j4) {
            float4 xq = Xq[j4], wa = W1a[j4], wb = W1b[j4];
            a0 = fmaf(wa.x, xq.x, a0); a0 = fmaf(wa.y, xq.y, a0);
            a0 = fmaf(wa.z, xq.z, a0); a0 = fmaf(wa.w, xq.w, a0);
            a1 = fmaf(wb.x, xq.x, a1); a1 = fmaf(wb.y, xq.y, a1);
            a1 = fmaf(wb.z, xq.z, a1); a1 = fmaf(wb.w, xq.w, a1);
        }
    }
    Hb[c]      = fast_tanh(a0);
    Hb[c + 32] = fast_tanh(a1);
    MEMFENCE();

    float xpv = b2[c];
    {
        const float4* Hq  = (const float4*)Hb;
        const float4* W2r = (const float4*)(W2 + c * HID);
        #pragma unroll
        for (int j4 = 0; j4 < HID / 4; ++j4) {
            float4 hq = Hq[j4], wq = W2r[j4];
            xpv = fmaf(wq.x, hq.x, xpv); xpv = fmaf(wq.y, hq.y, xpv);
            xpv = fmaf(wq.z, hq.z, xpv); xpv = fmaf(wq.w, hq.w, xpv);
        }
    }
    MEMFENCE();
    Sb[c] = xpv;                 // x_pred broadcast (xc is dead)
    MEMFENCE();

    // ---------------- innovation y[c] = meas[c] - (H x_pred)[c]; publish y
    float yv = meas[(size_t)item * D + c];
    {
        const float4* Hr = (const float4*)(Hm + c * D);   // per-lane row, L1-hot
        const float4* Xp = (const float4*)Sb;
        #pragma unroll
        for (int j4 = 0; j4 < D / 4; ++j4) {
            float4 hq = Hr[j4], xq = Xp[j4];
            yv = fmaf(-hq.x, xq.x, yv); yv = fmaf(-hq.y, xq.y, yv);
            yv = fmaf(-hq.z, xq.z, yv); yv = fmaf(-hq.w, xq.w, yv);
        }
    }
    Yb[c] = yv;                  // y lives at Sb[32..63] until the end
    MEMFENCE();

    // ---------------- P_pred column c (phase-local), HP column c
    float qc = __expf(logQ[c]);
    const float* Pp = P_post + (size_t)item * D * D;
    {
        float p[D];
        #pragma unroll
        for (int i = 0; i < D; ++i) p[i] = Pp[(size_t)i * D + c];
        #pragma unroll
        for (int i = 0; i < D; ++i) p[i] += (i == c) ? qc : 0.0f;

        float hp[D];
        #pragma unroll
        for (int i = 0; i < D; ++i) {
            const float* Hrow = Hm + i * D;               // uniform -> s_load
            float acc = 0.0f;
            #pragma unroll
            for (int j = 0; j < D; ++j) acc = fmaf(Hrow[j], p[j], acc);
            hp[i] = acc;
        }
        // HP rows -> Ts (stays intact through GJ and epilogue)
        #pragma unroll
        for (int i = 0; i < D; ++i) Ts[i * TPAD + c] = hp[i];
    }                            // p, hp dead here
    MEMFENCE();

    // ---------------- S column c: S[i][c] = sum_j H[i][j] * M[c][j] (+ diag)
    float s[D];
    {
        float mr[D];             // M row c, phase-local
        const float4* Tr = (const float4*)(Ts + c * TPAD);
        #pragma unroll
        for (int j4 = 0; j4 < D / 4; ++j4) {
            float4 q = Tr[j4];
            mr[4 * j4 + 0] = q.x; mr[4 * j4 + 1] = q.y;
            mr[4 * j4 + 2] = q.z; mr[4 * j4 + 3] = q.w;
        }
        #pragma unroll
        for (int i = 0; i < D; ++i) {
            const float* Hrow = Hm + i * D;               // uniform -> s_load
            float acc = 0.0f;
            #pragma unroll
            for (int j = 0; j < D; ++j) acc = fmaf(Hrow[j], mr[j], acc);
            s[i] = acc;
        }
    }                            // mr dead here
    float rc = __expf(logR[c]) + 1e-6f;
    #pragma unroll
    for (int i = 0; i < D; ++i) s[i] += (i == c) ? rc : 0.0f;

    // RHS column c = HP[:,c] (re-read from Ts; keeps hp's live range short)
    float wc[D];
    #pragma unroll
    for (int i = 0; i < D; ++i) wc[i] = Ts[i * TPAD + c];
    MEMFENCE();

    // ---------------- solve: wc := (S^-1 HP)[:,c]
    gj_all<0>(s, wc, Ub, c);

    // ---------------- x_upd[c] = x_pred[c] + (W^T y)[c] = xpv + sum_i wc[i] y[i]
    float xu = xpv;
    #pragma unroll
    for (int i4 = 0; i4 < D / 4; ++i4) {
        float4 yq = ((const float4*)Yb)[i4];
        xu = fmaf(wc[4 * i4 + 0], yq.x, xu);
        xu = fmaf(wc[4 * i4 + 1], yq.y, xu);
        xu = fmaf(wc[4 * i4 + 2], yq.z, xu);
        xu = fmaf(wc[4 * i4 + 3], yq.w, xu);
    }

    // ---------------- (M^T W)[i][c] = sum_j M[j][i] * wc[j]; M rows from Ts
    float acc[D];
    #pragma unroll
    for (int i = 0; i < D; ++i) acc[i] = 0.0f;
    #pragma unroll
    for (int j = 0; j < D; ++j) {
        float wj = wc[j];
        const float4* Tr = (const float4*)(Ts + j * TPAD);  // broadcast reads
        #pragma unroll
        for (int i4 = 0; i4 < D / 4; ++i4) {
            float4 q = Tr[i4];
            acc[4 * i4 + 0] = fmaf(q.x, wj, acc[4 * i4 + 0]);
            acc[4 * i4 + 1] = fmaf(q.y, wj, acc[4 * i4 + 1]);
            acc[4 * i4 + 2] = fmaf(q.z, wj, acc[4 * i4 + 2]);
            acc[4 * i4 + 3] = fmaf(q.w, wj, acc[4 * i4 + 3]);
        }
    }

    // ---------------- outputs; P_pred re-read scalar-wise (never an array)
    float* out_x = out;
    float* out_P = out + (size_t)B * D;
    out_x[(size_t)item * D + c] = xu;
    #pragma unroll
    for (int i = 0; i < D; ++i) {
        float pv = Pp[(size_t)i * D + c] + ((i == c) ? qc : 0.0f);
        out_P[(size_t)item * D * D + (size_t)i * D + c] = pv - acc[i];
    }
}

extern "C" void kernel_launch(void* const* d_in, const int* in_sizes, int n_in,
                              void* d_out, int out_size, void* d_ws, size_t ws_size,
                              hipStream_t stream) {
    const float* x_post = (const float*)d_in[0];
    const float* P_post = (const float*)d_in[1];
    const float* ctx    = (const float*)d_in[2];
    const float* meas   = (const float*)d_in[3];
    const float* W1     = (const float*)d_in[4];
    const float* b1     = (const float*)d_in[5];
    const float* W2     = (const float*)d_in[6];
    const float* b2     = (const float*)d_in[7];
    const float* Hm     = (const float*)d_in[8];
    const float* logQ   = (const float*)d_in[9];
    const float* logR   = (const float*)d_in[10];
    (void)n_in; (void)d_ws; (void)ws_size; (void)out_size;

    int B = in_sizes[0] / D;
    int blocks = (B + IPB - 1) / IPB;
    kalman_step_kernel<<<blocks, 256, 0, stream>>>(
        x_post, P_post, ctx, meas, W1, b1, W2, b2, Hm, logQ, logR,
        (float*)d_out, B);
}